// Round 1
// baseline (31790.695 us; speedup 1.0000x reference)
//
#include <hip/hip_runtime.h>
#include <math.h>

// ---------------------------------------------------------------------------
// MDN-RNN: LSTM(35 -> 256) over 1023 steps, batch 256, + MDN head
// (256 -> 100 -> 100 -> 170) with softmax/exp/reshape outputs.
//
// Design (round 0, fp32, correctness-first):
//  * Everything activation-like is stored TRANSPOSED: h_T[hid][b], so that
//    lane = batch index -> coalesced vector loads, and weight reads
//    W[row][k] are wave-uniform -> compiler emits scalar s_load (free pipe).
//  * One kernel launch per step s = 0..1026. Roles inside one kernel:
//      wg [0,128)    LSTM   : h_{s+1} = lstm(h_s, x_s)          (s <= 1022)
//      wg [128,153)  L1     : hid1 = relu(W1 h_s)    -> out s-1  (1<=s<=1023)
//      wg [153,178)  L2     : hid2 = relu(W2 hid1)   -> out s-2  (2<=s<=1024)
//      wg [178,221)  L3     : o    = W3 hid2 + b3    -> out s-3  (3<=s<=1025)
//      wg [221,237)  FIN    : softmax/exp/reshape    -> out s-4  (4<=s<=1026)
//    Each role reads buffers written by the PREVIOUS kernel (ping-pong
//    parity), so there are no intra-kernel races; stream order gives sync.
//  * x is transposed into [64 steps][35][256] windows every 64 steps.
// ---------------------------------------------------------------------------

#define HIDN   256
#define INDIM  35
#define BATCH  256
#define TSEQ   1024
#define NOUT   1023          // T-1 outputs
#define MDNH   100
#define KK     5
#define OCHN   170           // 2K + K*32

// ws layout in floats
#define OFF_HT   0                               // 2 * 256*256 (ping-pong h_T)
#define OFF_CT   (2*65536)                       // 256*256     (c_T, in-place)
#define OFF_H1   (3*65536)                       // 2 * 100*256
#define OFF_H2   (3*65536 + 2*25600)             // 2 * 100*256
#define OFF_OT   (3*65536 + 4*25600)             // 2 * 170*256
#define OFF_XW   (3*65536 + 4*25600 + 2*43520)   // 64*35*256
// total = 1,090,560 floats = 4.36 MB

#define MEANBASE (BATCH*NOUT*KK)                 // 1,309,440
#define VARBASE  (MEANBASE + BATCH*NOUT*KK*32)   // 43,211,520

__device__ __forceinline__ float sigf(float x) { return 1.0f / (1.0f + expf(-x)); }

// Transpose x[:, s0:s0+64, :] -> xw[tt][j][b]   (grid 256 = 64 tt * 4 btiles)
__global__ __launch_bounds__(256) void xpose_win(const float* __restrict__ x,
                                                 float* __restrict__ xw, int s0)
{
    __shared__ float tile[35 * 65];
    const int tt    = blockIdx.x >> 2;
    const int bbase = (blockIdx.x & 3) * 64;
    const int t     = s0 + tt;
    const int bo    = threadIdx.x >> 2;
    for (int j = (threadIdx.x & 3); j < 35; j += 4)
        tile[j * 65 + bo] =
            x[(size_t)(bbase + bo) * (TSEQ * INDIM) + (size_t)t * INDIM + j];
    __syncthreads();
    for (int idx = threadIdx.x; idx < 35 * 64; idx += 256) {
        int j = idx >> 6, b = idx & 63;
        xw[(tt * 35 + j) * 256 + bbase + b] = tile[j * 65 + b];
    }
}

__global__ __launch_bounds__(256) void step_kernel(
    const float* __restrict__ W_ih, const float* __restrict__ W_hh,
    const float* __restrict__ b_ih, const float* __restrict__ b_hh,
    const float* __restrict__ W1,   const float* __restrict__ b1,
    const float* __restrict__ W2,   const float* __restrict__ b2,
    const float* __restrict__ W3,   const float* __restrict__ b3,
    float* __restrict__ ws, float* __restrict__ out, int s)
{
    const int wg  = blockIdx.x;
    const int tid = threadIdx.x;

    if (wg < 128) {
        // ---------------- LSTM: 8 gate rows (2 hid units x 4 gates) --------
        if (s > 1022) return;
        const float* hsrc = ws + OFF_HT + (s & 1) * 65536;
        float*       hdst = ws + OFF_HT + ((s + 1) & 1) * 65536;
        float*       cT   = ws + OFF_CT;
        const float* xw   = ws + OFF_XW + (s & 63) * (35 * 256);
        const int h0 = wg * 2;
        const int b  = tid;

        float acc[8]; // acc[g*2+hh], gates i,f,g,o
        #pragma unroll
        for (int g = 0; g < 4; ++g)
            #pragma unroll
            for (int hh = 0; hh < 2; ++hh) {
                int row = g * 256 + h0 + hh;
                acc[g * 2 + hh] = b_ih[row] + b_hh[row];
            }

        #pragma unroll 4
        for (int k = 0; k < 256; ++k) {
            float hv = hsrc[k * 256 + b];          // coalesced, lane = batch
            #pragma unroll
            for (int g = 0; g < 4; ++g)
                #pragma unroll
                for (int hh = 0; hh < 2; ++hh)     // W_hh read is wave-uniform
                    acc[g * 2 + hh] =
                        fmaf(W_hh[(g * 256 + h0 + hh) * 256 + k], hv, acc[g * 2 + hh]);
        }
        #pragma unroll 5
        for (int j = 0; j < 35; ++j) {
            float xv = xw[j * 256 + b];
            #pragma unroll
            for (int g = 0; g < 4; ++g)
                #pragma unroll
                for (int hh = 0; hh < 2; ++hh)
                    acc[g * 2 + hh] =
                        fmaf(W_ih[(g * 256 + h0 + hh) * 35 + j], xv, acc[g * 2 + hh]);
        }
        #pragma unroll
        for (int hh = 0; hh < 2; ++hh) {
            const int hidx = h0 + hh;
            float iv = sigf(acc[0 + hh]);
            float fv = sigf(acc[2 + hh]);
            float gv = tanhf(acc[4 + hh]);
            float ov = sigf(acc[6 + hh]);
            float c  = fv * cT[hidx * 256 + b] + iv * gv;
            cT[hidx * 256 + b]   = c;
            hdst[hidx * 256 + b] = ov * tanhf(c);
        }
    } else if (wg < 153) {
        // ---------------- L1: hid1 = relu(h_s @ W1^T + b1), out-idx s-1 ----
        if (s < 1 || s > 1023) return;
        const float* hsrc = ws + OFF_HT + (s & 1) * 65536;
        float*       dst  = ws + OFF_H1 + (s & 1) * 25600;
        const int ch0 = (wg - 128) * 4;
        const int b   = tid;
        float acc[4];
        #pragma unroll
        for (int c = 0; c < 4; ++c) acc[c] = b1[ch0 + c];
        #pragma unroll 4
        for (int k = 0; k < 256; ++k) {
            float hv = hsrc[k * 256 + b];
            #pragma unroll
            for (int c = 0; c < 4; ++c)
                acc[c] = fmaf(W1[(ch0 + c) * 256 + k], hv, acc[c]);
        }
        #pragma unroll
        for (int c = 0; c < 4; ++c)
            dst[(ch0 + c) * 256 + b] = fmaxf(acc[c], 0.0f);
    } else if (wg < 178) {
        // ---------------- L2: hid2 = relu(hid1 @ W2^T + b2), out-idx s-2 ---
        if (s < 2 || s > 1024) return;
        const float* src = ws + OFF_H1 + ((s - 1) & 1) * 25600;
        float*       dst = ws + OFF_H2 + (s & 1) * 25600;
        const int ch0 = (wg - 153) * 4;
        const int b   = tid;
        float acc[4];
        #pragma unroll
        for (int c = 0; c < 4; ++c) acc[c] = b2[ch0 + c];
        #pragma unroll 4
        for (int k = 0; k < 100; ++k) {
            float hv = src[k * 256 + b];
            #pragma unroll
            for (int c = 0; c < 4; ++c)
                acc[c] = fmaf(W2[(ch0 + c) * 100 + k], hv, acc[c]);
        }
        #pragma unroll
        for (int c = 0; c < 4; ++c)
            dst[(ch0 + c) * 256 + b] = fmaxf(acc[c], 0.0f);
    } else if (wg < 221) {
        // ---------------- L3: o = hid2 @ W3^T + b3, out-idx s-3 ------------
        if (s < 3 || s > 1025) return;
        const float* src = ws + OFF_H2 + ((s - 1) & 1) * 25600;
        float*       dst = ws + OFF_OT + (s & 1) * 43520;
        const int ch0 = (wg - 178) * 4;
        const int nch = (ch0 + 4 <= OCHN) ? 4 : (OCHN - ch0);
        const int b   = tid;
        float acc[4] = {0.f, 0.f, 0.f, 0.f};
        for (int c = 0; c < nch; ++c) acc[c] = b3[ch0 + c];
        #pragma unroll 4
        for (int k = 0; k < 100; ++k) {
            float hv = src[k * 256 + b];
            #pragma unroll
            for (int c = 0; c < 4; ++c)
                if (c < nch)
                    acc[c] = fmaf(W3[(ch0 + c) * 100 + k], hv, acc[c]);
        }
        for (int c = 0; c < nch; ++c)
            dst[(ch0 + c) * 256 + b] = acc[c];
    } else if (wg < 237) {
        // ---------------- FIN: softmax/exp/reshape to d_out, out-idx s-4 ---
        if (s < 4 || s > 1026) return;
        const int t     = s - 4;
        const int bbase = (wg - 221) * 16;
        const float* src = ws + OFF_OT + ((s - 1) & 1) * 43520;
        __shared__ float tile[16 * 172];
        __shared__ float smax[16], sinv[16];
        for (int idx = tid; idx < OCHN * 16; idx += 256) {
            int ch = idx >> 4, bb = idx & 15;
            tile[bb * 172 + ch] = src[ch * 256 + bbase + bb];
        }
        __syncthreads();
        if (tid < 16) {
            float m = tile[tid * 172 + 0];
            #pragma unroll
            for (int k = 1; k < KK; ++k) m = fmaxf(m, tile[tid * 172 + k]);
            float den = 0.f;
            #pragma unroll
            for (int k = 0; k < KK; ++k) den += expf(tile[tid * 172 + k] - m);
            smax[tid] = m;
            sinv[tid] = 1.0f / den;
        }
        __syncthreads();
        for (int idx = tid; idx < 16 * OCHN; idx += 256) {
            int bb = idx / OCHN, ch = idx - bb * OCHN;
            int bg = bbase + bb;
            float v = tile[bb * 172 + ch];
            if (ch < KK) {
                out[(size_t)bg * (NOUT * KK) + (size_t)t * KK + ch] =
                    expf(v - smax[bb]) * sinv[bb];
            } else if (ch < 2 * KK) {
                out[VARBASE + (size_t)bg * (NOUT * KK) + (size_t)t * KK + (ch - KK)] =
                    expf(v);
            } else {
                out[MEANBASE + ((size_t)bg * NOUT + t) * 160 + (ch - 2 * KK)] = v;
            }
        }
    }
}

extern "C" void kernel_launch(void* const* d_in, const int* in_sizes, int n_in,
                              void* d_out, int out_size, void* d_ws, size_t ws_size,
                              hipStream_t stream)
{
    const float* x    = (const float*)d_in[0];
    const float* W_ih = (const float*)d_in[1];
    const float* W_hh = (const float*)d_in[2];
    const float* b_ih = (const float*)d_in[3];
    const float* b_hh = (const float*)d_in[4];
    const float* W1   = (const float*)d_in[5];
    const float* b1   = (const float*)d_in[6];
    const float* W2   = (const float*)d_in[7];
    const float* b2   = (const float*)d_in[8];
    const float* W3   = (const float*)d_in[9];
    const float* b3   = (const float*)d_in[10];
    float* out = (float*)d_out;
    float* ws  = (float*)d_ws;

    // zero h_0 (ping buffer 0) and c state every call (deterministic)
    hipMemsetAsync(ws + OFF_HT, 0, 65536 * sizeof(float), stream);
    hipMemsetAsync(ws + OFF_CT, 0, 65536 * sizeof(float), stream);

    for (int s = 0; s <= 1026; ++s) {
        if (s <= 1022 && (s & 63) == 0)
            xpose_win<<<256, 256, 0, stream>>>(x, ws + OFF_XW, s);
        step_kernel<<<237, 256, 0, stream>>>(W_ih, W_hh, b_ih, b_hh,
                                             W1, b1, W2, b2, W3, b3,
                                             ws, out, s);
    }
}

// Round 2
// 20728.883 us; speedup vs baseline: 1.5336x; 1.5336x over previous
//
#include <hip/hip_runtime.h>
#include <math.h>

// ---------------------------------------------------------------------------
// MDN-RNN round 2: weight-stationary-in-L2, gate-packed float4 weights.
// Thread owns (unit, batch) with all 4 gate accs -> per k: 1x float4 W load
// + 1x float h load + 4 FMA. Roles pipelined across launches as round 1.
//   wg [0,256)    LSTM   (s <= 1022)   h_{s+1} = lstm(h_s, x_s)
//   wg [256,384)  L1     (1<=s<=1023)  relu(W1 h_s)         -> out s-1
//   wg [384,512)  L2     (2<=s<=1024)  relu(W2 hid1)        -> out s-2
//   wg [512,768)  L3     (3<=s<=1025)  W3 hid2 + b3         -> out s-3
//   wg [768,784)  FIN    (4<=s<=1026)  softmax/exp/reshape  -> out s-4
// ---------------------------------------------------------------------------

#define TSEQ  1024
#define NOUT  1023
#define KK    5
#define OCHN  170

// ws layout (floats)
#define OFF_HT   0                  // 2 x 65536 ping-pong h_T[hid][b]
#define OFF_CT   131072             // 65536 c_T[hid][b]
#define OFF_H1   196608             // 2 x 32768 ([128ch][256b], ch<100 used)
#define OFF_H2   262144             // 2 x 32768
#define OFF_OT   327680             // 2 x 43520 ([170ch][256b])
#define OFF_XW   414720             // 64*35*256 x-window transposed
#define OFF_WHH  988160             // 256k x 256u x 4g floats (float4[65536])
#define OFF_WIH  1250304            // 35j x 256u x 4g floats (float4[8960])
#define OFF_BG   1286144            // 256u x 4g combined bias
#define OFF_W1T  1287168            // 256k x 128ch (ch<100)
#define OFF_W2T  1319936            // 100k x 128ch
#define OFF_W3T  1332736            // 100k x 192ch (ch<170)
// total 1,351,936 floats = 5.4 MB

#define MEANBASE (256 * NOUT * KK)
#define VARBASE  (MEANBASE + 256 * NOUT * KK * 32)

__device__ __forceinline__ float sigf(float x) { return 1.0f / (1.0f + expf(-x)); }

// --------------------------- one-time weight pack ---------------------------
__global__ __launch_bounds__(256) void prep_pack(
    const float* __restrict__ W_ih, const float* __restrict__ W_hh,
    const float* __restrict__ b_ih, const float* __restrict__ b_hh,
    const float* __restrict__ W1,   const float* __restrict__ W2,
    const float* __restrict__ W3,   float* __restrict__ ws)
{
    const int idx = blockIdx.x * 256 + threadIdx.x;
    if (idx < 65536) {                         // Wg_hh[k][u][g] float4
        int k = idx >> 8, u = idx & 255;
        float4 v;
        v.x = W_hh[(0 * 256 + u) * 256 + k];
        v.y = W_hh[(1 * 256 + u) * 256 + k];
        v.z = W_hh[(2 * 256 + u) * 256 + k];
        v.w = W_hh[(3 * 256 + u) * 256 + k];
        ((float4*)(ws + OFF_WHH))[idx] = v;
    } else if (idx < 74496) {                  // Wg_ih[j][u][g] float4
        int r = idx - 65536;
        int j = r >> 8, u = r & 255;
        float4 v;
        v.x = W_ih[(0 * 256 + u) * 35 + j];
        v.y = W_ih[(1 * 256 + u) * 35 + j];
        v.z = W_ih[(2 * 256 + u) * 35 + j];
        v.w = W_ih[(3 * 256 + u) * 35 + j];
        ((float4*)(ws + OFF_WIH))[r] = v;
    } else if (idx < 74752) {                  // biasg[u][g]
        int u = idx - 74496;
        float4 v;
        v.x = b_ih[0 * 256 + u] + b_hh[0 * 256 + u];
        v.y = b_ih[1 * 256 + u] + b_hh[1 * 256 + u];
        v.z = b_ih[2 * 256 + u] + b_hh[2 * 256 + u];
        v.w = b_ih[3 * 256 + u] + b_hh[3 * 256 + u];
        ((float4*)(ws + OFF_BG))[u] = v;
    } else if (idx < 107520) {                 // W1T[k][128]
        int r = idx - 74752;
        int k = r >> 7, c = r & 127;
        if (c < 100) ws[OFF_W1T + k * 128 + c] = W1[c * 256 + k];
    } else if (idx < 120320) {                 // W2T[k][128]
        int r = idx - 107520;
        int k = r >> 7, c = r & 127;
        if (c < 100) ws[OFF_W2T + k * 128 + c] = W2[c * 100 + k];
    } else if (idx < 139520) {                 // W3T[k][192]
        int r = idx - 120320;
        int k = r / 192, c = r - k * 192;
        if (c < 170) ws[OFF_W3T + k * 192 + c] = W3[c * 100 + k];
    }
}

// ------------------- x window transpose: [64t][35j][256b] -------------------
__global__ __launch_bounds__(256) void xpose_win(const float* __restrict__ x,
                                                 float* __restrict__ xw, int s0)
{
    __shared__ float tile[35 * 65];
    const int tt    = blockIdx.x >> 2;
    const int bbase = (blockIdx.x & 3) * 64;
    const int t     = s0 + tt;
    const int bo    = threadIdx.x >> 2;
    for (int j = (threadIdx.x & 3); j < 35; j += 4)
        tile[j * 65 + bo] =
            x[(size_t)(bbase + bo) * (TSEQ * 35) + (size_t)t * 35 + j];
    __syncthreads();
    for (int idx = threadIdx.x; idx < 35 * 64; idx += 256) {
        int j = idx >> 6, b = idx & 63;
        xw[(tt * 35 + j) * 256 + bbase + b] = tile[j * 65 + b];
    }
}

// ------------------------------- step kernel --------------------------------
__global__ __launch_bounds__(256) void step_kernel(
    const float* __restrict__ b1, const float* __restrict__ b2,
    const float* __restrict__ b3,
    float* __restrict__ ws, float* __restrict__ out, int s)
{
    const int wg  = blockIdx.x;
    const int tid = threadIdx.x;

    if (wg < 256) {
        // ---------------- LSTM ----------------
        if (s > 1022) return;
        const float*  hsrc = ws + OFF_HT + (s & 1) * 65536;
        float*        hdst = ws + OFF_HT + ((s + 1) & 1) * 65536;
        float*        cT   = ws + OFF_CT;
        const float*  xw   = ws + OFF_XW + (s & 63) * (35 * 256);
        const float4* Wg   = (const float4*)(ws + OFF_WHH);
        const float4* Wx   = (const float4*)(ws + OFF_WIH);
        const float4* Bg   = (const float4*)(ws + OFF_BG);

        const int u = (wg >> 4) * 16 + (tid >> 4);
        const int b = (wg & 15) * 16 + (tid & 15);

        float4 acc = Bg[u];
        #pragma unroll 8
        for (int k = 0; k < 256; ++k) {
            float  hv = hsrc[k * 256 + b];
            float4 w  = Wg[k * 256 + u];
            acc.x = fmaf(w.x, hv, acc.x);
            acc.y = fmaf(w.y, hv, acc.y);
            acc.z = fmaf(w.z, hv, acc.z);
            acc.w = fmaf(w.w, hv, acc.w);
        }
        #pragma unroll 5
        for (int j = 0; j < 35; ++j) {
            float  xv = xw[j * 256 + b];
            float4 w  = Wx[j * 256 + u];
            acc.x = fmaf(w.x, xv, acc.x);
            acc.y = fmaf(w.y, xv, acc.y);
            acc.z = fmaf(w.z, xv, acc.z);
            acc.w = fmaf(w.w, xv, acc.w);
        }
        float iv = sigf(acc.x);
        float fv = sigf(acc.y);
        float gv = tanhf(acc.z);
        float ov = sigf(acc.w);
        float c  = fv * cT[u * 256 + b] + iv * gv;
        cT[u * 256 + b]   = c;
        hdst[u * 256 + b] = ov * tanhf(c);
    } else if (wg < 384) {
        // ---------------- L1: relu(W1 h_s + b1), out-idx s-1 ----------------
        if (s < 1 || s > 1023) return;
        const float* hsrc = ws + OFF_HT + (s & 1) * 65536;
        float*       dst  = ws + OFF_H1 + (s & 1) * 32768;
        const float* W1T  = ws + OFF_W1T;
        const int ch = tid & 127, bb = tid >> 7;
        if (ch >= 100) return;
        const int b = (wg - 256) * 2 + bb;
        float acc = b1[ch];
        #pragma unroll 8
        for (int k = 0; k < 256; ++k)
            acc = fmaf(W1T[k * 128 + ch], hsrc[k * 256 + b], acc);
        dst[ch * 256 + b] = fmaxf(acc, 0.0f);
    } else if (wg < 512) {
        // ---------------- L2: relu(W2 hid1 + b2), out-idx s-2 ---------------
        if (s < 2 || s > 1024) return;
        const float* src = ws + OFF_H1 + ((s - 1) & 1) * 32768;
        float*       dst = ws + OFF_H2 + (s & 1) * 32768;
        const float* W2T = ws + OFF_W2T;
        const int ch = tid & 127, bb = tid >> 7;
        if (ch >= 100) return;
        const int b = (wg - 384) * 2 + bb;
        float acc = b2[ch];
        #pragma unroll 4
        for (int k = 0; k < 100; ++k)
            acc = fmaf(W2T[k * 128 + ch], src[k * 256 + b], acc);
        dst[ch * 256 + b] = fmaxf(acc, 0.0f);
    } else if (wg < 768) {
        // ---------------- L3: W3 hid2 + b3, out-idx s-3 ---------------------
        if (s < 3 || s > 1025) return;
        const float* src = ws + OFF_H2 + ((s - 1) & 1) * 32768;
        float*       dst = ws + OFF_OT + (s & 1) * 43520;
        const float* W3T = ws + OFF_W3T;
        const int ch = tid;
        if (ch >= 170) return;
        const int b = wg - 512;
        float acc = b3[ch];
        #pragma unroll 4
        for (int k = 0; k < 100; ++k)
            acc = fmaf(W3T[k * 192 + ch], src[k * 256 + b], acc);
        dst[ch * 256 + b] = acc;
    } else {
        // ---------------- FIN: softmax/exp/reshape, out-idx s-4 -------------
        if (s < 4 || s > 1026) return;
        const int t     = s - 4;
        const int bbase = (wg - 768) * 16;
        const float* src = ws + OFF_OT + ((s - 1) & 1) * 43520;
        __shared__ float tile[16 * 172];
        __shared__ float smax[16], sinv[16];
        for (int idx = tid; idx < OCHN * 16; idx += 256) {
            int ch = idx >> 4, bb = idx & 15;
            tile[bb * 172 + ch] = src[ch * 256 + bbase + bb];
        }
        __syncthreads();
        if (tid < 16) {
            float m = tile[tid * 172 + 0];
            #pragma unroll
            for (int k = 1; k < KK; ++k) m = fmaxf(m, tile[tid * 172 + k]);
            float den = 0.f;
            #pragma unroll
            for (int k = 0; k < KK; ++k) den += expf(tile[tid * 172 + k] - m);
            smax[tid] = m;
            sinv[tid] = 1.0f / den;
        }
        __syncthreads();
        for (int idx = tid; idx < 16 * OCHN; idx += 256) {
            int bb = idx / OCHN, ch = idx - bb * OCHN;
            int bg = bbase + bb;
            float v = tile[bb * 172 + ch];
            if (ch < KK) {
                out[(size_t)bg * (NOUT * KK) + (size_t)t * KK + ch] =
                    expf(v - smax[bb]) * sinv[bb];
            } else if (ch < 2 * KK) {
                out[VARBASE + (size_t)bg * (NOUT * KK) + (size_t)t * KK + (ch - KK)] =
                    expf(v);
            } else {
                out[MEANBASE + ((size_t)bg * NOUT + t) * 160 + (ch - 2 * KK)] = v;
            }
        }
    }
}

extern "C" void kernel_launch(void* const* d_in, const int* in_sizes, int n_in,
                              void* d_out, int out_size, void* d_ws, size_t ws_size,
                              hipStream_t stream)
{
    const float* x    = (const float*)d_in[0];
    const float* W_ih = (const float*)d_in[1];
    const float* W_hh = (const float*)d_in[2];
    const float* b_ih = (const float*)d_in[3];
    const float* b_hh = (const float*)d_in[4];
    const float* W1   = (const float*)d_in[5];
    const float* b1   = (const float*)d_in[6];
    const float* W2   = (const float*)d_in[7];
    const float* b2   = (const float*)d_in[8];
    const float* W3   = (const float*)d_in[9];
    const float* b3   = (const float*)d_in[10];
    float* out = (float*)d_out;
    float* ws  = (float*)d_ws;

    hipMemsetAsync(ws + OFF_HT, 0, 65536 * sizeof(float), stream);
    hipMemsetAsync(ws + OFF_CT, 0, 65536 * sizeof(float), stream);
    prep_pack<<<545, 256, 0, stream>>>(W_ih, W_hh, b_ih, b_hh, W1, W2, W3, ws);

    for (int s = 0; s <= 1026; ++s) {
        if (s <= 1022 && (s & 63) == 0)
            xpose_win<<<256, 256, 0, stream>>>(x, ws + OFF_XW, s);
        step_kernel<<<784, 256, 0, stream>>>(b1, b2, b3, ws, out, s);
    }
}